// Round 2
// baseline (216.783 us; speedup 1.0000x reference)
//
#include <hip/hip_runtime.h>
#include <math.h>

#define EPS 1e-7f
#define REG_MAX 16
#define NC 80
#define A_DIM 8400
#define TOTAL (32 * 8400)

// ws layout (bytes):
//   [0..11]   float acc[3]  : sum_liou, sum_dfl, num_fg
//   [16..19]  int   count   : number of fg anchors
//   [64.. ]   int   idx[TOTAL] : compacted fg pair-indices
__global__ __launch_bounds__(256) void fg_compact(
    const int* __restrict__ fg_mask, int* __restrict__ idx_out, int* __restrict__ count)
{
    const int i = blockIdx.x * blockDim.x + threadIdx.x;
    const bool fg = fg_mask[i] != 0;
    const unsigned long long ball = __ballot(fg);
    const int lane = threadIdx.x & 63;
    const int pre = __popcll(ball & ((1ull << lane) - 1ull));
    const int tot = __popcll(ball);
    int base = 0;
    if (lane == 0 && tot > 0) base = atomicAdd(count, tot);
    base = __shfl(base, 0);
    if (fg) idx_out[base + pre] = i;
}

__global__ __launch_bounds__(256) void bbox_loss_main(
    const float* __restrict__ pred_dist,      // (B,A,64)
    const float* __restrict__ pred_bboxes,    // (B,A,4)
    const float* __restrict__ anchor_points,  // (A,2)
    const float* __restrict__ target_bboxes,  // (B,A,4)
    const float* __restrict__ target_scores,  // (B,A,80)
    const int* __restrict__ idx,
    const int* __restrict__ count,
    float* __restrict__ acc)
{
    const int j = blockIdx.x * blockDim.x + threadIdx.x;
    const int n = *count;

    float liou = 0.f, ldfl = 0.f, nfg = 0.f;

    if (j < n) {
        const int i = idx[j];
        nfg = 1.f;
        const int a = i % A_DIM;
        const float ax = anchor_points[2 * a + 0];
        const float ay = anchor_points[2 * a + 1];

        const float4 pb = *(const float4*)(pred_bboxes + (size_t)i * 4);
        const float4 tb = *(const float4*)(target_bboxes + (size_t)i * 4);

        // ---- weight = sum of 80 class scores ----
        const float4* ts = (const float4*)(target_scores + (size_t)i * NC);
        float w = 0.f;
        #pragma unroll
        for (int k = 0; k < NC / 4; ++k) {
            float4 v = ts[k];
            w += v.x + v.y + v.z + v.w;
        }

        // ---- CIoU ----
        const float x11 = pb.x, y11 = pb.y, x21 = pb.z, y21 = pb.w;
        const float x12 = tb.x, y12 = tb.y, x22 = tb.z, y22 = tb.w;
        const float iw = fmaxf(fminf(x21, x22) - fmaxf(x11, x12), 0.f);
        const float ih = fmaxf(fminf(y21, y22) - fmaxf(y11, y12), 0.f);
        const float inter = iw * ih;
        const float w1 = x21 - x11, h1 = y21 - y11;
        const float w2 = x22 - x12, h2 = y22 - y12;
        const float uni = w1 * h1 + w2 * h2 - inter + EPS;
        const float iou = inter / uni;
        const float cw = fmaxf(x21, x22) - fminf(x11, x12);
        const float ch = fmaxf(y21, y22) - fminf(y11, y12);
        const float c2 = cw * cw + ch * ch + EPS;
        const float dx = x11 + x21 - x12 - x22;
        const float dy = y11 + y21 - y12 - y22;
        const float rho2 = (dx * dx + dy * dy) * 0.25f;
        const float dang = atanf(w1 / (h1 + EPS)) - atanf(w2 / (h2 + EPS));
        const float v = (4.f / (float)(M_PI * M_PI)) * dang * dang;
        const float alpha = v / (1.f - iou + v + EPS);
        const float ciou = iou - (rho2 / c2 + v * alpha);
        liou = (1.f - ciou) * w;

        // ---- DFL ----
        float t[4];
        t[0] = fminf(fmaxf(ax - tb.x, 0.f), (float)(REG_MAX - 1) - 0.01f);
        t[1] = fminf(fmaxf(ay - tb.y, 0.f), (float)(REG_MAX - 1) - 0.01f);
        t[2] = fminf(fmaxf(tb.z - ax, 0.f), (float)(REG_MAX - 1) - 0.01f);
        t[3] = fminf(fmaxf(tb.w - ay, 0.f), (float)(REG_MAX - 1) - 0.01f);

        const float* pd = pred_dist + (size_t)i * (4 * REG_MAX);
        float dfl = 0.f;
        #pragma unroll
        for (int s = 0; s < 4; ++s) {
            float x[REG_MAX];
            const float4* p4 = (const float4*)(pd + s * REG_MAX);
            #pragma unroll
            for (int k = 0; k < REG_MAX / 4; ++k) {
                float4 vv = p4[k];
                x[4 * k + 0] = vv.x; x[4 * k + 1] = vv.y;
                x[4 * k + 2] = vv.z; x[4 * k + 3] = vv.w;
            }
            float m = x[0];
            #pragma unroll
            for (int k = 1; k < REG_MAX; ++k) m = fmaxf(m, x[k]);
            float se = 0.f;
            #pragma unroll
            for (int k = 0; k < REG_MAX; ++k) se += __expf(x[k] - m);
            const float lse = m + __logf(se);
            const int tl = (int)t[s];
            const int tr = min(tl + 1, REG_MAX - 1);
            const float wl = (float)(tl + 1) - t[s];
            const float wr = 1.f - wl;
            dfl += (lse - x[tl]) * wl + (lse - x[tr]) * wr;
        }
        ldfl = dfl;
    }

    // ---- reduction: wave shuffle -> LDS -> one atomicAdd per block ----
    #pragma unroll
    for (int off = 32; off > 0; off >>= 1) {
        liou += __shfl_down(liou, off);
        ldfl += __shfl_down(ldfl, off);
        nfg  += __shfl_down(nfg, off);
    }
    __shared__ float s0[4], s1[4], s2[4];
    const int wave = threadIdx.x >> 6;
    const int lane = threadIdx.x & 63;
    if (lane == 0) { s0[wave] = liou; s1[wave] = ldfl; s2[wave] = nfg; }
    __syncthreads();
    if (threadIdx.x == 0) {
        float a0 = 0.f, a1 = 0.f, a2 = 0.f;
        #pragma unroll
        for (int k = 0; k < 4; ++k) { a0 += s0[k]; a1 += s1[k]; a2 += s2[k]; }
        if (a2 != 0.f) {
            atomicAdd(&acc[0], a0);
            atomicAdd(&acc[1], a1);
            atomicAdd(&acc[2], a2);
        }
    }
}

__global__ void bbox_loss_finalize(const float* __restrict__ acc,
                                   const float* __restrict__ tss,
                                   float* __restrict__ out)
{
    out[0] = acc[0] / tss[0];
    out[1] = acc[1] / fmaxf(acc[2] * 4.f, 1.f);
}

extern "C" void kernel_launch(void* const* d_in, const int* in_sizes, int n_in,
                              void* d_out, int out_size, void* d_ws, size_t ws_size,
                              hipStream_t stream) {
    const float* pred_dist     = (const float*)d_in[0];
    const float* pred_bboxes   = (const float*)d_in[1];
    const float* anchor_points = (const float*)d_in[2];
    const float* target_bboxes = (const float*)d_in[3];
    const float* target_scores = (const float*)d_in[4];
    const float* tss           = (const float*)d_in[5];
    const int*   fg_mask       = (const int*)d_in[6];
    float* out = (float*)d_out;

    float* acc   = (float*)d_ws;
    int*   count = (int*)((char*)d_ws + 16);
    int*   idx   = (int*)((char*)d_ws + 64);

    const int total = in_sizes[6];                 // B*A = 268800
    const int block = 256;
    const int grid = (total + block - 1) / block;  // 1050

    hipMemsetAsync(d_ws, 0, 32, stream);           // zero acc + count
    fg_compact<<<grid, block, 0, stream>>>(fg_mask, idx, count);
    bbox_loss_main<<<grid, block, 0, stream>>>(pred_dist, pred_bboxes, anchor_points,
                                               target_bboxes, target_scores, idx, count, acc);
    bbox_loss_finalize<<<1, 1, 0, stream>>>(acc, tss, out);
}

// Round 3
// 170.252 us; speedup vs baseline: 1.2733x; 1.2733x over previous
//
#include <hip/hip_runtime.h>
#include <math.h>

#define EPS 1e-7f
#define REG_MAX 16
#define NC 80
#define A_DIM 8400
#define TOTAL (32 * 8400)

// ws layout (floats), each accumulator on its own 128B line:
//   [0]   = sum_liou
//   [32]  = sum_dfl
//   [64]  = num_fg
//   [96]  = count (int)
//   [128..] = idx[TOTAL]
#define ACC_LIOU 0
#define ACC_DFL  32
#define ACC_NFG  64
#define ACC_CNT  96
#define IDX_OFF  128

__global__ __launch_bounds__(1024) void fg_compact(
    const int* __restrict__ fg_mask, int* __restrict__ idx_out,
    int* __restrict__ count, int total)
{
    __shared__ int wave_tot[16];
    __shared__ int s_base;
    const int i = blockIdx.x * 1024 + threadIdx.x;
    const int wave = threadIdx.x >> 6;
    const int lane = threadIdx.x & 63;
    const bool fg = (i < total) && (fg_mask[i] != 0);
    const unsigned long long ball = __ballot(fg);
    const int pre = __popcll(ball & ((1ull << lane) - 1ull));
    const int tot = __popcll(ball);
    if (lane == 0) wave_tot[wave] = tot;
    __syncthreads();
    if (threadIdx.x == 0) {
        int bt = 0;
        #pragma unroll
        for (int k = 0; k < 16; ++k) bt += wave_tot[k];
        s_base = (bt > 0) ? atomicAdd(count, bt) : 0;
    }
    __syncthreads();
    if (fg) {
        int woff = 0;
        for (int k = 0; k < wave; ++k) woff += wave_tot[k];
        idx_out[s_base + woff + pre] = i;
    }
}

__global__ __launch_bounds__(256) void bbox_loss_main(
    const float* __restrict__ pred_dist,      // (B,A,64)
    const float* __restrict__ pred_bboxes,    // (B,A,4)
    const float* __restrict__ anchor_points,  // (A,2)
    const float* __restrict__ target_bboxes,  // (B,A,4)
    const float* __restrict__ target_scores,  // (B,A,80)
    const int* __restrict__ idx,
    const int* __restrict__ count,
    float* __restrict__ acc)
{
    const int n = *count;
    if (blockIdx.x * 256 >= n) return;   // idle blocks: out before any work
    const int j = blockIdx.x * 256 + threadIdx.x;

    float liou = 0.f, ldfl = 0.f, nfg = 0.f;

    if (j < n) {
        const int i = idx[j];
        nfg = 1.f;
        const int a = i % A_DIM;
        const float ax = anchor_points[2 * a + 0];
        const float ay = anchor_points[2 * a + 1];

        const float4 pb = *(const float4*)(pred_bboxes + (size_t)i * 4);
        const float4 tb = *(const float4*)(target_bboxes + (size_t)i * 4);

        // ---- weight = sum of 80 class scores ----
        const float4* ts = (const float4*)(target_scores + (size_t)i * NC);
        float w = 0.f;
        #pragma unroll
        for (int k = 0; k < NC / 4; ++k) {
            float4 v = ts[k];
            w += v.x + v.y + v.z + v.w;
        }

        // ---- CIoU ----
        const float x11 = pb.x, y11 = pb.y, x21 = pb.z, y21 = pb.w;
        const float x12 = tb.x, y12 = tb.y, x22 = tb.z, y22 = tb.w;
        const float iw = fmaxf(fminf(x21, x22) - fmaxf(x11, x12), 0.f);
        const float ih = fmaxf(fminf(y21, y22) - fmaxf(y11, y12), 0.f);
        const float inter = iw * ih;
        const float w1 = x21 - x11, h1 = y21 - y11;
        const float w2 = x22 - x12, h2 = y22 - y12;
        const float uni = w1 * h1 + w2 * h2 - inter + EPS;
        const float iou = inter / uni;
        const float cw = fmaxf(x21, x22) - fminf(x11, x12);
        const float ch = fmaxf(y21, y22) - fminf(y11, y12);
        const float c2 = cw * cw + ch * ch + EPS;
        const float dx = x11 + x21 - x12 - x22;
        const float dy = y11 + y21 - y12 - y22;
        const float rho2 = (dx * dx + dy * dy) * 0.25f;
        const float dang = atanf(w1 / (h1 + EPS)) - atanf(w2 / (h2 + EPS));
        const float v = (4.f / (float)(M_PI * M_PI)) * dang * dang;
        const float alpha = v / (1.f - iou + v + EPS);
        const float ciou = iou - (rho2 / c2 + v * alpha);
        liou = (1.f - ciou) * w;

        // ---- DFL ----
        float t[4];
        t[0] = fminf(fmaxf(ax - tb.x, 0.f), (float)(REG_MAX - 1) - 0.01f);
        t[1] = fminf(fmaxf(ay - tb.y, 0.f), (float)(REG_MAX - 1) - 0.01f);
        t[2] = fminf(fmaxf(tb.z - ax, 0.f), (float)(REG_MAX - 1) - 0.01f);
        t[3] = fminf(fmaxf(tb.w - ay, 0.f), (float)(REG_MAX - 1) - 0.01f);

        const float* pd = pred_dist + (size_t)i * (4 * REG_MAX);
        float dfl = 0.f;
        #pragma unroll
        for (int s = 0; s < 4; ++s) {
            float x[REG_MAX];
            const float4* p4 = (const float4*)(pd + s * REG_MAX);
            #pragma unroll
            for (int k = 0; k < REG_MAX / 4; ++k) {
                float4 vv = p4[k];
                x[4 * k + 0] = vv.x; x[4 * k + 1] = vv.y;
                x[4 * k + 2] = vv.z; x[4 * k + 3] = vv.w;
            }
            float m = x[0];
            #pragma unroll
            for (int k = 1; k < REG_MAX; ++k) m = fmaxf(m, x[k]);
            float se = 0.f;
            #pragma unroll
            for (int k = 0; k < REG_MAX; ++k) se += __expf(x[k] - m);
            const float lse = m + __logf(se);
            const int tl = (int)t[s];
            const int tr = min(tl + 1, REG_MAX - 1);
            const float wl = (float)(tl + 1) - t[s];
            const float wr = 1.f - wl;
            dfl += (lse - x[tl]) * wl + (lse - x[tr]) * wr;
        }
        ldfl = dfl;
    }

    // ---- reduction: wave shuffle -> LDS -> one atomicAdd per block per line ----
    #pragma unroll
    for (int off = 32; off > 0; off >>= 1) {
        liou += __shfl_down(liou, off);
        ldfl += __shfl_down(ldfl, off);
        nfg  += __shfl_down(nfg, off);
    }
    __shared__ float s0[4], s1[4], s2[4];
    const int wave = threadIdx.x >> 6;
    const int lane = threadIdx.x & 63;
    if (lane == 0) { s0[wave] = liou; s1[wave] = ldfl; s2[wave] = nfg; }
    __syncthreads();
    if (threadIdx.x == 0) {
        float a0 = 0.f, a1 = 0.f, a2 = 0.f;
        #pragma unroll
        for (int k = 0; k < 4; ++k) { a0 += s0[k]; a1 += s1[k]; a2 += s2[k]; }
        atomicAdd(&acc[ACC_LIOU], a0);   // separate 128B lines: parallel service
        atomicAdd(&acc[ACC_DFL],  a1);
        atomicAdd(&acc[ACC_NFG],  a2);
    }
}

__global__ void bbox_loss_finalize(const float* __restrict__ acc,
                                   const float* __restrict__ tss,
                                   float* __restrict__ out)
{
    out[0] = acc[ACC_LIOU] / tss[0];
    out[1] = acc[ACC_DFL] / fmaxf(acc[ACC_NFG] * 4.f, 1.f);
}

extern "C" void kernel_launch(void* const* d_in, const int* in_sizes, int n_in,
                              void* d_out, int out_size, void* d_ws, size_t ws_size,
                              hipStream_t stream) {
    const float* pred_dist     = (const float*)d_in[0];
    const float* pred_bboxes   = (const float*)d_in[1];
    const float* anchor_points = (const float*)d_in[2];
    const float* target_bboxes = (const float*)d_in[3];
    const float* target_scores = (const float*)d_in[4];
    const float* tss           = (const float*)d_in[5];
    const int*   fg_mask       = (const int*)d_in[6];
    float* out = (float*)d_out;

    float* acc   = (float*)d_ws;
    int*   count = (int*)((float*)d_ws + ACC_CNT);
    int*   idx   = (int*)((float*)d_ws + IDX_OFF);

    const int total = in_sizes[6];                 // B*A = 268800

    hipMemsetAsync(d_ws, 0, IDX_OFF * sizeof(float), stream);  // zero acc lines + count
    fg_compact<<<(total + 1023) / 1024, 1024, 0, stream>>>(fg_mask, idx, count, total);
    bbox_loss_main<<<(total + 255) / 256, 256, 0, stream>>>(pred_dist, pred_bboxes,
                                                            anchor_points, target_bboxes,
                                                            target_scores, idx, count, acc);
    bbox_loss_finalize<<<1, 1, 0, stream>>>(acc, tss, out);
}

// Round 4
// 167.591 us; speedup vs baseline: 1.2935x; 1.0159x over previous
//
#include <hip/hip_runtime.h>
#include <math.h>

#define EPS 1e-7f
#define REG_MAX 16
#define A_DIM 8400

// d_ws layout (floats): p_liou[0..2047], p_dfl[2048..4095], p_nfg[4096..6143]
// (one slot per block, written unconditionally -> no memset, no atomics)

__global__ __launch_bounds__(256) void bbox_loss_fused(
    const float* __restrict__ pred_dist,      // (B,A,64)
    const float* __restrict__ pred_bboxes,    // (B,A,4)
    const float* __restrict__ anchor_points,  // (A,2)
    const float* __restrict__ target_bboxes,  // (B,A,4)
    const float* __restrict__ target_scores,  // (B,A,80)
    const int*   __restrict__ fg_mask,        // (B,A) int32
    float* __restrict__ p_liou,
    float* __restrict__ p_dfl,
    float* __restrict__ p_nfg,
    int total)
{
    __shared__ int s_idx[256];
    __shared__ int s_wtot[4];
    __shared__ int s_woff[4];
    __shared__ int s_cnt;

    const int tid  = threadIdx.x;
    const int i0   = blockIdx.x * 256 + tid;
    const int wave = tid >> 6;
    const int lane = tid & 63;

    // ---- block-local stream compaction into LDS ----
    const bool fg = (i0 < total) && (fg_mask[i0] != 0);
    const unsigned long long ball = __ballot(fg);
    const int pre = __popcll(ball & ((1ull << lane) - 1ull));
    if (lane == 0) s_wtot[wave] = __popcll(ball);
    __syncthreads();
    if (tid == 0) {
        int off = 0;
        #pragma unroll
        for (int k = 0; k < 4; ++k) { s_woff[k] = off; off += s_wtot[k]; }
        s_cnt = off;
    }
    __syncthreads();
    if (fg) s_idx[s_woff[wave] + pre] = i0;
    __syncthreads();
    const int cnt = s_cnt;

    // ---- cooperative processing: 16 lanes per fg item ----
    float liou = 0.f, ldfl = 0.f;

    const int g  = tid >> 4;   // group 0..15
    const int gl = tid & 15;   // lane within group
    const int q  = gl >> 2;    // side 0..3 (l,t,r,b)
    const int ql = gl & 3;     // lane within quad

    for (int j = g; j < cnt; j += 16) {
        const int i = s_idx[j];
        const int a = i % A_DIM;

        // weight = sum of 80 class scores, split across 16 lanes (20 float4s)
        const float4* ts4 = (const float4*)(target_scores + (size_t)i * 80);
        float4 v = ts4[gl];
        float w = v.x + v.y + v.z + v.w;
        if (gl < 4) { float4 u = ts4[16 + gl]; w += u.x + u.y + u.z + u.w; }
        #pragma unroll
        for (int off = 8; off >= 1; off >>= 1) w += __shfl_xor(w, off);

        const float4 tb = *(const float4*)(target_bboxes + (size_t)i * 4);
        const float ax = anchor_points[2 * a];
        const float ay = anchor_points[2 * a + 1];

        // ---- DFL: quad q owns side q's 16-bin softmax, 4 bins per lane ----
        float tq = (q == 0) ? (ax - tb.x) : (q == 1) ? (ay - tb.y)
                 : (q == 2) ? (tb.z - ax) : (tb.w - ay);
        tq = fminf(fmaxf(tq, 0.f), (float)(REG_MAX - 1) - 0.01f);

        const float4 x4 = ((const float4*)(pred_dist + (size_t)i * 64))[q * 4 + ql];
        float m = fmaxf(fmaxf(x4.x, x4.y), fmaxf(x4.z, x4.w));
        m = fmaxf(m, __shfl_xor(m, 1));
        m = fmaxf(m, __shfl_xor(m, 2));
        float se = __expf(x4.x - m) + __expf(x4.y - m)
                 + __expf(x4.z - m) + __expf(x4.w - m);
        se += __shfl_xor(se, 1);
        se += __shfl_xor(se, 2);
        const float lse = m + __logf(se);

        const int   tl = (int)tq;
        const int   tr = min(tl + 1, REG_MAX - 1);
        const float wl = (float)(tl + 1) - tq;
        const float wr = 1.f - wl;
        const int base = ql * 4;
        float s = 0.f;
        int r = tl - base;
        if (r >= 0 && r < 4) s += wl * (r == 0 ? x4.x : r == 1 ? x4.y : r == 2 ? x4.z : x4.w);
        r = tr - base;
        if (r >= 0 && r < 4) s += wr * (r == 0 ? x4.x : r == 1 ? x4.y : r == 2 ? x4.z : x4.w);
        s += __shfl_xor(s, 1);
        s += __shfl_xor(s, 2);
        if (ql == 0) ldfl += lse - s;   // ce_l*wl + ce_r*wr for this side

        // ---- CIoU on the group leader ----
        if (gl == 0) {
            const float4 pb = *(const float4*)(pred_bboxes + (size_t)i * 4);
            const float x11 = pb.x, y11 = pb.y, x21 = pb.z, y21 = pb.w;
            const float x12 = tb.x, y12 = tb.y, x22 = tb.z, y22 = tb.w;
            const float iw = fmaxf(fminf(x21, x22) - fmaxf(x11, x12), 0.f);
            const float ih = fmaxf(fminf(y21, y22) - fmaxf(y11, y12), 0.f);
            const float inter = iw * ih;
            const float w1 = x21 - x11, h1 = y21 - y11;
            const float w2 = x22 - x12, h2 = y22 - y12;
            const float uni = w1 * h1 + w2 * h2 - inter + EPS;
            const float iou = inter / uni;
            const float cw = fmaxf(x21, x22) - fminf(x11, x12);
            const float ch = fmaxf(y21, y22) - fminf(y11, y12);
            const float c2 = cw * cw + ch * ch + EPS;
            const float dx = x11 + x21 - x12 - x22;
            const float dy = y11 + y21 - y12 - y22;
            const float rho2 = (dx * dx + dy * dy) * 0.25f;
            const float dang = atanf(w1 / (h1 + EPS)) - atanf(w2 / (h2 + EPS));
            const float vv = (4.f / (float)(M_PI * M_PI)) * dang * dang;
            const float alpha = vv / (1.f - iou + vv + EPS);
            const float ciou = iou - (rho2 / c2 + vv * alpha);
            liou += (1.f - ciou) * w;
        }
    }

    // ---- block reduction -> per-block partial slots (no atomics) ----
    #pragma unroll
    for (int off = 32; off >= 1; off >>= 1) {
        liou += __shfl_down(liou, off);
        ldfl += __shfl_down(ldfl, off);
    }
    __shared__ float r0[4], r1[4];
    if (lane == 0) { r0[wave] = liou; r1[wave] = ldfl; }
    __syncthreads();
    if (tid == 0) {
        p_liou[blockIdx.x] = r0[0] + r0[1] + r0[2] + r0[3];
        p_dfl[blockIdx.x]  = r1[0] + r1[1] + r1[2] + r1[3];
        p_nfg[blockIdx.x]  = (float)cnt;
    }
}

__global__ __launch_bounds__(256) void bbox_loss_finalize(
    const float* __restrict__ p_liou,
    const float* __restrict__ p_dfl,
    const float* __restrict__ p_nfg,
    int nb,
    const float* __restrict__ tss,
    float* __restrict__ out)
{
    const int tid = threadIdx.x;
    float a = 0.f, b = 0.f, c = 0.f;
    for (int k = tid; k < nb; k += 256) {
        a += p_liou[k];
        b += p_dfl[k];
        c += p_nfg[k];
    }
    #pragma unroll
    for (int off = 32; off >= 1; off >>= 1) {
        a += __shfl_down(a, off);
        b += __shfl_down(b, off);
        c += __shfl_down(c, off);
    }
    __shared__ float r0[4], r1[4], r2[4];
    const int wave = tid >> 6, lane = tid & 63;
    if (lane == 0) { r0[wave] = a; r1[wave] = b; r2[wave] = c; }
    __syncthreads();
    if (tid == 0) {
        const float A = r0[0] + r0[1] + r0[2] + r0[3];
        const float Bs = r1[0] + r1[1] + r1[2] + r1[3];
        const float C = r2[0] + r2[1] + r2[2] + r2[3];
        out[0] = A / tss[0];
        out[1] = Bs / fmaxf(C * 4.f, 1.f);
    }
}

extern "C" void kernel_launch(void* const* d_in, const int* in_sizes, int n_in,
                              void* d_out, int out_size, void* d_ws, size_t ws_size,
                              hipStream_t stream) {
    const float* pred_dist     = (const float*)d_in[0];
    const float* pred_bboxes   = (const float*)d_in[1];
    const float* anchor_points = (const float*)d_in[2];
    const float* target_bboxes = (const float*)d_in[3];
    const float* target_scores = (const float*)d_in[4];
    const float* tss           = (const float*)d_in[5];
    const int*   fg_mask       = (const int*)d_in[6];
    float* out = (float*)d_out;

    float* p_liou = (float*)d_ws;
    float* p_dfl  = p_liou + 2048;
    float* p_nfg  = p_liou + 4096;

    const int total = in_sizes[6];               // B*A = 268800
    const int nb = (total + 255) / 256;          // 1050

    bbox_loss_fused<<<nb, 256, 0, stream>>>(pred_dist, pred_bboxes, anchor_points,
                                            target_bboxes, target_scores, fg_mask,
                                            p_liou, p_dfl, p_nfg, total);
    bbox_loss_finalize<<<1, 256, 0, stream>>>(p_liou, p_dfl, p_nfg, nb, tss, out);
}